// Round 2
// baseline (1100.306 us; speedup 1.0000x reference)
//
#include <hip/hip_runtime.h>
#include <stdint.h>

// Problem dims
#define TOK 2048   // B*S
#define DD  1024   // D
#define RH  4096   // router hidden H
#define HE  4096   // expert hidden
#define NE  8      // experts
#define CH  2048   // combiner hidden 2D
#define MAXTILE 40    // max 128-row tiles across experts: 4096/128 + 7 = 39
#define MAXROWS 5120  // 4096 pairs + 8*127 pad, rounded up
#define KSG2 4     // split-K slices for expert GEMM2 (K=4096 -> 1024 each)
#define KSC1 2     // split-K for combiner GEMM1 (K=1024 -> 512)
#define KSC2 4     // split-K for combiner GEMM2 (K=2048 -> 512)

using bf16x8 = __attribute__((ext_vector_type(8))) short;
using f32x4  = __attribute__((ext_vector_type(4))) float;

__device__ __forceinline__ unsigned short f2bf(float f) {
  union { float f; uint32_t u; } v; v.f = f;
  uint32_t r = (v.u + 0x7fffu + ((v.u >> 16) & 1u)) >> 16;
  return (unsigned short)r;
}
__device__ __forceinline__ float bf2f(unsigned short h) {
  union { uint32_t u; float f; } v; v.u = ((uint32_t)h) << 16;
  return v.f;
}
__device__ __forceinline__ float gelu_f(float x) {
  return 0.5f * x * (1.0f + erff(x * 0.70710678118654752440f));
}

// async global->LDS, 16B per lane; LDS dest = wave-uniform base + lane*16
#define GLD(SRC, DST) __builtin_amdgcn_global_load_lds( \
    (const __attribute__((address_space(1))) uint32_t*)(const void*)(SRC), \
    (__attribute__((address_space(3))) uint32_t*)(void*)(DST), 16, 0, 0)

// block (256 threads) LN stats over 1024 values (4 per thread already summed)
__device__ __forceinline__ void block_ln_stats(float s1, float s2, float& mean, float& rstd) {
  #pragma unroll
  for (int off = 32; off > 0; off >>= 1) {
    s1 += __shfl_down(s1, off);
    s2 += __shfl_down(s2, off);
  }
  __shared__ float sh[8];
  int tid = threadIdx.x;
  if ((tid & 63) == 0) { sh[tid >> 6] = s1; sh[4 + (tid >> 6)] = s2; }
  __syncthreads();
  float t1 = sh[0] + sh[1] + sh[2] + sh[3];
  float t2 = sh[4] + sh[5] + sh[6] + sh[7];
  mean = t1 * (1.0f / 1024.0f);
  float var = t2 * (1.0f / 1024.0f) - mean * mean;
  rstd = rsqrtf(var + 1e-5f);
}

// ---- h = x + pos_encoding; shared LN stats; xhat fp32 + bf16 hi/lo ----
// also zeroes bucketing state (folds 4 memsets); paired sincosf halves trig cost
__global__ void k_prep(const float* __restrict__ x, float* __restrict__ h,
                       float* __restrict__ xh32, unsigned short* __restrict__ xhi,
                       unsigned short* __restrict__ xlo, int* __restrict__ cnt,
                       int* __restrict__ fillc, int* __restrict__ nflag,
                       int* __restrict__ tok_of) {
  int t = blockIdx.x;
  int s = t & 1023;
  int tid = threadIdx.x;
  float4 xv = ((const float4*)(x + (size_t)t * DD))[tid];
  float v[4]; float s1 = 0.f, s2 = 0.f;
  #pragma unroll
  for (int kp = 0; kp < 2; ++kp) {
    float i2 = (float)(tid * 4 + kp * 2);   // even d shared by (sin,cos) pair
    float div = expf(-9.2103403719761836f * i2 * (1.0f / 1024.0f));
    float ang = (float)s * div;
    float sn, cs;
    sincosf(ang, &sn, &cs);
    float xe = (kp == 0) ? xv.x : xv.z;
    float xo = (kp == 0) ? xv.y : xv.w;
    v[kp * 2] = xe + sn; v[kp * 2 + 1] = xo + cs;
  }
  #pragma unroll
  for (int k = 0; k < 4; ++k) { s1 += v[k]; s2 += v[k] * v[k]; }
  float mean, rstd;
  block_ln_stats(s1, s2, mean, rstd);
  float4 ho; ho.x = v[0]; ho.y = v[1]; ho.z = v[2]; ho.w = v[3];
  ((float4*)(h + (size_t)t * DD))[tid] = ho;
  float xn[4]; unsigned short hh[4], ll[4];
  #pragma unroll
  for (int k = 0; k < 4; ++k) {
    xn[k] = (v[k] - mean) * rstd;
    hh[k] = f2bf(xn[k]);
    ll[k] = f2bf(xn[k] - bf2f(hh[k]));
  }
  float4 xo4; xo4.x = xn[0]; xo4.y = xn[1]; xo4.z = xn[2]; xo4.w = xn[3];
  ((float4*)(xh32 + (size_t)t * DD))[tid] = xo4;
  ushort4 h4; h4.x = hh[0]; h4.y = hh[1]; h4.z = hh[2]; h4.w = hh[3];
  ((ushort4*)(xhi + (size_t)t * DD))[tid] = h4;
  ushort4 l4; l4.x = ll[0]; l4.y = ll[1]; l4.z = ll[2]; l4.w = ll[3];
  ((ushort4*)(xlo + (size_t)t * DD))[tid] = l4;
  if (t == 0) {
    for (int i = tid; i < MAXROWS; i += 256) tok_of[i] = 0;
    if (tid < NE) { cnt[tid] = 0; fillc[tid] = 0; }
    if (tid == 0) nflag[0] = 0;
  }
}

// ---- transpose+convert weights: in fp32 [D,N] (opt row-scale g[D]) -> out bf16 [N,D] ----
__global__ void k_tconv(const float* __restrict__ in, const float* __restrict__ g,
                        unsigned short* __restrict__ out, int D, int N,
                        long long in_bs, long long g_bs, long long out_bs) {
  __shared__ float tile[64][65];
  int e = blockIdx.z;
  const float* inb = in + (size_t)e * in_bs;
  unsigned short* outb = out + (size_t)e * out_bs;
  int n0 = blockIdx.x * 64, d0 = blockIdx.y * 64;
  int c4 = threadIdx.x & 15;   // 16 float4 per 64-wide row
  int r0 = threadIdx.x >> 4;   // 16 rows per pass
  #pragma unroll
  for (int rr = 0; rr < 4; ++rr) {
    int dl = r0 + rr * 16;
    float4 v = *(const float4*)(inb + (size_t)(d0 + dl) * N + n0 + c4 * 4);
    if (g) {
      float gv = g[(size_t)e * g_bs + d0 + dl];
      v.x *= gv; v.y *= gv; v.z *= gv; v.w *= gv;
    }
    tile[dl][c4 * 4 + 0] = v.x; tile[dl][c4 * 4 + 1] = v.y;
    tile[dl][c4 * 4 + 2] = v.z; tile[dl][c4 * 4 + 3] = v.w;
  }
  __syncthreads();
  int q = threadIdx.x & 15;
  int nb = threadIdx.x >> 4;
  #pragma unroll
  for (int rr = 0; rr < 4; ++rr) {
    int nl = nb + rr * 16;
    ushort4 o;
    o.x = f2bf(tile[q * 4 + 0][nl]); o.y = f2bf(tile[q * 4 + 1][nl]);
    o.z = f2bf(tile[q * 4 + 2][nl]); o.w = f2bf(tile[q * 4 + 3][nl]);
    *(ushort4*)(outb + (size_t)(n0 + nl) * D + d0 + q * 4) = o;
  }
}

// router variant: writes bf16 hi, bf16 lo, and fp32 transposed copies
__global__ void k_tconv_split(const float* __restrict__ in, const float* __restrict__ g,
                              unsigned short* __restrict__ oh, unsigned short* __restrict__ ol,
                              float* __restrict__ o32, int D, int N) {
  __shared__ float tile[32][33];
  int n0 = blockIdx.x * 32, d0 = blockIdx.y * 32;
  int tn = threadIdx.x & 31, tr = threadIdx.x >> 5;
  #pragma unroll
  for (int rr = 0; rr < 4; ++rr) {
    int dl = tr + rr * 8;
    float v = in[(size_t)(d0 + dl) * N + n0 + tn];
    if (g) v *= g[d0 + dl];
    tile[dl][tn] = v;
  }
  __syncthreads();
  #pragma unroll
  for (int rr = 0; rr < 4; ++rr) {
    int nl = tr + rr * 8;
    float v = tile[tn][nl];
    size_t off = (size_t)(n0 + nl) * D + d0 + tn;
    unsigned short hi = f2bf(v);
    oh[off] = hi;
    ol[off] = f2bf(v - bf2f(hi));
    o32[off] = v;
  }
}

// ---- bias fold: out[n] = b1[n] + sum_d lnb[d]*w[d,n]  (skips w reads if lnb[d]==0) ----
__global__ void k_foldbias(const float* __restrict__ w, const float* __restrict__ lnb,
                           const float* __restrict__ b1, float* __restrict__ outb,
                           int D, int N, long long w_bs, long long lnb_bs,
                           long long b_bs, long long o_bs) {
  int e = blockIdx.y;
  int n = blockIdx.x * 256 + threadIdx.x;
  const float* wb = w + (size_t)e * w_bs;
  const float* lb = lnb + (size_t)e * lnb_bs;
  float acc = b1[(size_t)e * b_bs + n];
  for (int d = 0; d < D; ++d) {
    float l = lb[d];
    if (l != 0.f) acc += l * wb[(size_t)d * N + n];
  }
  outb[(size_t)e * o_bs + n] = acc;
}

// ---- dense split-K GEMM, 2-phase dbuf: partial[z][M,N] = A @ Bt^T (fp32, no bias) ----
__global__ __launch_bounds__(256)
void k_gemm_sk(const unsigned short* __restrict__ A, const unsigned short* __restrict__ B,
               float* __restrict__ C, int N, int K, int kslice, long long c_slice) {
  __shared__ __align__(16) unsigned short As[2][4096];
  __shared__ __align__(16) unsigned short Bs[2][4096];
  const int tid = threadIdx.x;
  const int w = tid >> 6, lane = tid & 63;
  const int q = lane >> 4, r16 = lane & 15;
  const int kz = blockIdx.z;
  const int n0 = blockIdx.x * 128, m0 = blockIdx.y * 128;
  f32x4 acc[4][4];
  #pragma unroll
  for (int i = 0; i < 4; ++i)
    #pragma unroll
    for (int j = 0; j < 4; ++j) acc[i][j] = (f32x4){0.f, 0.f, 0.f, 0.f};
  const int srow = w * 32 + (lane >> 2);
  const int scol = (lane & 3) * 8;
  const unsigned short* a_src = A + (size_t)(m0 + srow) * K + scol + (size_t)kz * kslice;
  const unsigned short* b_src = B + (size_t)(n0 + srow) * K + scol + (size_t)kz * kslice;
  const int wm = w >> 1, wn = w & 1;
  GLD(a_src, &As[0][w * 1024]);
  GLD(a_src + (size_t)16 * K, &As[0][w * 1024 + 512]);
  GLD(b_src, &Bs[0][w * 1024]);
  GLD(b_src + (size_t)16 * K, &Bs[0][w * 1024 + 512]);
  __syncthreads();
  int cur = 0;
  for (int kt = 0; kt < kslice; kt += 32) {
    int nk = kt + 32;
    if (nk < kslice) {
      GLD(a_src + nk, &As[cur ^ 1][w * 1024]);
      GLD(a_src + nk + (size_t)16 * K, &As[cur ^ 1][w * 1024 + 512]);
      GLD(b_src + nk, &Bs[cur ^ 1][w * 1024]);
      GLD(b_src + nk + (size_t)16 * K, &Bs[cur ^ 1][w * 1024 + 512]);
    }
    bf16x8 af[4], bfv[4];
    #pragma unroll
    for (int i = 0; i < 4; ++i)
      af[i] = *(const bf16x8*)&As[cur][(wm * 64 + i * 16 + r16) * 32 + q * 8];
    #pragma unroll
    for (int j = 0; j < 4; ++j)
      bfv[j] = *(const bf16x8*)&Bs[cur][(wn * 64 + j * 16 + r16) * 32 + q * 8];
    #pragma unroll
    for (int i = 0; i < 4; ++i)
      #pragma unroll
      for (int j = 0; j < 4; ++j)
        acc[i][j] = __builtin_amdgcn_mfma_f32_16x16x32_bf16(af[i], bfv[j], acc[i][j], 0, 0, 0);
    __syncthreads();
    cur ^= 1;
  }
  #pragma unroll
  for (int j = 0; j < 4; ++j) {
    int col = n0 + wn * 64 + j * 16 + r16;
    #pragma unroll
    for (int i = 0; i < 4; ++i) {
      int row = m0 + wm * 64 + i * 16 + q * 4;
      #pragma unroll
      for (int t2 = 0; t2 < 4; ++t2)
        C[(size_t)kz * c_slice + (size_t)(row + t2) * N + col] = acc[i][j][t2];
    }
  }
}

// ---- reduce split-K partials + bias + gelu -> bf16 (N must be pow2) ----
__global__ void k_redg(const float* __restrict__ p, const float* __restrict__ bias,
                       unsigned short* __restrict__ o, int N, long long slice, int nsl) {
  size_t i = ((size_t)blockIdx.x * 256 + threadIdx.x) * 4;
  float4 a = *(const float4*)(p + i);
  for (int s = 1; s < nsl; ++s) {
    float4 b = *(const float4*)(p + (size_t)s * slice + i);
    a.x += b.x; a.y += b.y; a.z += b.z; a.w += b.w;
  }
  int col = (int)(i & (size_t)(N - 1));
  float4 bv = *(const float4*)(bias + col);
  ushort4 u;
  u.x = f2bf(gelu_f(a.x + bv.x)); u.y = f2bf(gelu_f(a.y + bv.y));
  u.z = f2bf(gelu_f(a.z + bv.z)); u.w = f2bf(gelu_f(a.w + bv.w));
  *(ushort4*)(o + i) = u;
}

// ---- grouped expert GEMM1, 2-phase dbuf: gathered tokens -> gelu -> F1g [slot][RH] ----
__global__ __launch_bounds__(256)
void k_gemm_g1(const unsigned short* __restrict__ A, const unsigned short* __restrict__ W,
               const float* __restrict__ bias, unsigned short* __restrict__ C,
               const int* __restrict__ tok_of, const int* __restrict__ tile_e,
               const int* __restrict__ tile_r0, const int* __restrict__ ntiles) {
  if ((int)blockIdx.y >= *ntiles) return;
  __shared__ __align__(16) unsigned short As[2][4096];
  __shared__ __align__(16) unsigned short Bs[2][4096];
  const int tid = threadIdx.x;
  const int w = tid >> 6, lane = tid & 63;
  const int q = lane >> 4, r16 = lane & 15;
  const int e = tile_e[blockIdx.y];
  const int row0 = tile_r0[blockIdx.y];
  const int n0 = blockIdx.x * 128;
  f32x4 acc[4][4];
  #pragma unroll
  for (int i = 0; i < 4; ++i)
    #pragma unroll
    for (int j = 0; j < 4; ++j) acc[i][j] = (f32x4){0.f, 0.f, 0.f, 0.f};
  const int srow = w * 32 + (lane >> 2);
  const int scol = (lane & 3) * 8;
  const int t0 = tok_of[row0 + srow];
  const int t1 = tok_of[row0 + srow + 16];
  const unsigned short* a_src0 = A + (size_t)t0 * DD + scol;
  const unsigned short* a_src1 = A + (size_t)t1 * DD + scol;
  const unsigned short* b_src = W + (size_t)e * RH * DD + (size_t)(n0 + srow) * DD + scol;
  const int wm = w >> 1, wn = w & 1;
  GLD(a_src0, &As[0][w * 1024]);
  GLD(a_src1, &As[0][w * 1024 + 512]);
  GLD(b_src, &Bs[0][w * 1024]);
  GLD(b_src + (size_t)16 * DD, &Bs[0][w * 1024 + 512]);
  __syncthreads();
  int cur = 0;
  for (int kt = 0; kt < DD; kt += 32) {
    int nk = kt + 32;
    if (nk < DD) {
      GLD(a_src0 + nk, &As[cur ^ 1][w * 1024]);
      GLD(a_src1 + nk, &As[cur ^ 1][w * 1024 + 512]);
      GLD(b_src + nk, &Bs[cur ^ 1][w * 1024]);
      GLD(b_src + nk + (size_t)16 * DD, &Bs[cur ^ 1][w * 1024 + 512]);
    }
    bf16x8 af[4], bfv[4];
    #pragma unroll
    for (int i = 0; i < 4; ++i)
      af[i] = *(const bf16x8*)&As[cur][(wm * 64 + i * 16 + r16) * 32 + q * 8];
    #pragma unroll
    for (int j = 0; j < 4; ++j)
      bfv[j] = *(const bf16x8*)&Bs[cur][(wn * 64 + j * 16 + r16) * 32 + q * 8];
    #pragma unroll
    for (int i = 0; i < 4; ++i)
      #pragma unroll
      for (int j = 0; j < 4; ++j)
        acc[i][j] = __builtin_amdgcn_mfma_f32_16x16x32_bf16(af[i], bfv[j], acc[i][j], 0, 0, 0);
    __syncthreads();
    cur ^= 1;
  }
  #pragma unroll
  for (int j = 0; j < 4; ++j) {
    int col = n0 + wn * 64 + j * 16 + r16;
    float bv = bias[(size_t)e * RH + col];
    #pragma unroll
    for (int i = 0; i < 4; ++i) {
      int row = row0 + wm * 64 + i * 16 + q * 4;
      #pragma unroll
      for (int t2 = 0; t2 < 4; ++t2)
        C[(size_t)(row + t2) * RH + col] = f2bf(gelu_f(acc[i][j][t2] + bv));
    }
  }
}

// ---- grouped expert GEMM2, split-K + 2-phase dbuf -> fp32 partial[z][slot][DD] ----
__global__ __launch_bounds__(256)
void k_gemm_g2(const unsigned short* __restrict__ A, const unsigned short* __restrict__ W,
               float* __restrict__ C, const int* __restrict__ tile_e,
               const int* __restrict__ tile_r0, const int* __restrict__ ntiles) {
  if ((int)blockIdx.y >= *ntiles) return;
  __shared__ __align__(16) unsigned short As[2][4096];
  __shared__ __align__(16) unsigned short Bs[2][4096];
  const int tid = threadIdx.x;
  const int w = tid >> 6, lane = tid & 63;
  const int q = lane >> 4, r16 = lane & 15;
  const int e = tile_e[blockIdx.y];
  const int row0 = tile_r0[blockIdx.y];
  const int n0 = blockIdx.x * 128;
  const int kz = blockIdx.z;            // K slice: [kz*1024, (kz+1)*1024)
  f32x4 acc[4][4];
  #pragma unroll
  for (int i = 0; i < 4; ++i)
    #pragma unroll
    for (int j = 0; j < 4; ++j) acc[i][j] = (f32x4){0.f, 0.f, 0.f, 0.f};
  const int srow = w * 32 + (lane >> 2);
  const int scol = (lane & 3) * 8;
  const unsigned short* a_src = A + (size_t)(row0 + srow) * HE + scol + (size_t)kz * (HE / KSG2);
  const unsigned short* b_src = W + (size_t)e * DD * HE + (size_t)(n0 + srow) * HE + scol
                                + (size_t)kz * (HE / KSG2);
  const int wm = w >> 1, wn = w & 1;
  GLD(a_src, &As[0][w * 1024]);
  GLD(a_src + (size_t)16 * HE, &As[0][w * 1024 + 512]);
  GLD(b_src, &Bs[0][w * 1024]);
  GLD(b_src + (size_t)16 * HE, &Bs[0][w * 1024 + 512]);
  __syncthreads();
  int cur = 0;
  for (int kt = 0; kt < HE / KSG2; kt += 32) {
    int nk = kt + 32;
    if (nk < HE / KSG2) {
      GLD(a_src + nk, &As[cur ^ 1][w * 1024]);
      GLD(a_src + nk + (size_t)16 * HE, &As[cur ^ 1][w * 1024 + 512]);
      GLD(b_src + nk, &Bs[cur ^ 1][w * 1024]);
      GLD(b_src + nk + (size_t)16 * HE, &Bs[cur ^ 1][w * 1024 + 512]);
    }
    bf16x8 af[4], bfv[4];
    #pragma unroll
    for (int i = 0; i < 4; ++i)
      af[i] = *(const bf16x8*)&As[cur][(wm * 64 + i * 16 + r16) * 32 + q * 8];
    #pragma unroll
    for (int j = 0; j < 4; ++j)
      bfv[j] = *(const bf16x8*)&Bs[cur][(wn * 64 + j * 16 + r16) * 32 + q * 8];
    #pragma unroll
    for (int i = 0; i < 4; ++i)
      #pragma unroll
      for (int j = 0; j < 4; ++j)
        acc[i][j] = __builtin_amdgcn_mfma_f32_16x16x32_bf16(af[i], bfv[j], acc[i][j], 0, 0, 0);
    __syncthreads();
    cur ^= 1;
  }
  #pragma unroll
  for (int j = 0; j < 4; ++j) {
    int col = n0 + wn * 64 + j * 16 + r16;
    #pragma unroll
    for (int i = 0; i < 4; ++i) {
      int row = row0 + wm * 64 + i * 16 + q * 4;
      #pragma unroll
      for (int t2 = 0; t2 < 4; ++t2)
        C[(size_t)kz * MAXROWS * DD + (size_t)(row + t2) * DD + col] = acc[i][j][t2];
    }
  }
}

// ---- split-precision router GEMM1, 2-phase dbuf: (Ah+Al)@(Bh+Bl)^T, gelu, fp32 out ----
__global__ __launch_bounds__(256)
void k_gemm_split(const unsigned short* __restrict__ Ah, const unsigned short* __restrict__ Al,
                  const unsigned short* __restrict__ Bh, const unsigned short* __restrict__ Bl,
                  const float* __restrict__ bias, float* __restrict__ C, int N, int K) {
  __shared__ __align__(16) unsigned short Ahs[2][4096];
  __shared__ __align__(16) unsigned short Als[2][4096];
  __shared__ __align__(16) unsigned short Bhs[2][4096];
  __shared__ __align__(16) unsigned short Bls[2][4096];
  const int tid = threadIdx.x;
  const int w = tid >> 6, lane = tid & 63;
  const int q = lane >> 4, r16 = lane & 15;
  const int n0 = blockIdx.x * 128, m0 = blockIdx.y * 128;
  f32x4 acc[4][4];
  #pragma unroll
  for (int i = 0; i < 4; ++i)
    #pragma unroll
    for (int j = 0; j < 4; ++j) acc[i][j] = (f32x4){0.f, 0.f, 0.f, 0.f};
  const int srow = w * 32 + (lane >> 2);
  const int scol = (lane & 3) * 8;
  const unsigned short* ah_src = Ah + (size_t)(m0 + srow) * K + scol;
  const unsigned short* al_src = Al + (size_t)(m0 + srow) * K + scol;
  const unsigned short* bh_src = Bh + (size_t)(n0 + srow) * K + scol;
  const unsigned short* bl_src = Bl + (size_t)(n0 + srow) * K + scol;
  const int wm = w >> 1, wn = w & 1;
  GLD(ah_src, &Ahs[0][w * 1024]);
  GLD(ah_src + (size_t)16 * K, &Ahs[0][w * 1024 + 512]);
  GLD(al_src, &Als[0][w * 1024]);
  GLD(al_src + (size_t)16 * K, &Als[0][w * 1024 + 512]);
  GLD(bh_src, &Bhs[0][w * 1024]);
  GLD(bh_src + (size_t)16 * K, &Bhs[0][w * 1024 + 512]);
  GLD(bl_src, &Bls[0][w * 1024]);
  GLD(bl_src + (size_t)16 * K, &Bls[0][w * 1024 + 512]);
  __syncthreads();
  int cur = 0;
  for (int kt = 0; kt < K; kt += 32) {
    int nk = kt + 32;
    if (nk < K) {
      GLD(ah_src + nk, &Ahs[cur ^ 1][w * 1024]);
      GLD(ah_src + nk + (size_t)16 * K, &Ahs[cur ^ 1][w * 1024 + 512]);
      GLD(al_src + nk, &Als[cur ^ 1][w * 1024]);
      GLD(al_src + nk + (size_t)16 * K, &Als[cur ^ 1][w * 1024 + 512]);
      GLD(bh_src + nk, &Bhs[cur ^ 1][w * 1024]);
      GLD(bh_src + nk + (size_t)16 * K, &Bhs[cur ^ 1][w * 1024 + 512]);
      GLD(bl_src + nk, &Bls[cur ^ 1][w * 1024]);
      GLD(bl_src + nk + (size_t)16 * K, &Bls[cur ^ 1][w * 1024 + 512]);
    }
    bf16x8 ah[4], al[4], bh[4], bl[4];
    #pragma unroll
    for (int i = 0; i < 4; ++i) {
      int o = (wm * 64 + i * 16 + r16) * 32 + q * 8;
      ah[i] = *(const bf16x8*)&Ahs[cur][o];
      al[i] = *(const bf16x8*)&Als[cur][o];
    }
    #pragma unroll
    for (int j = 0; j < 4; ++j) {
      int o = (wn * 64 + j * 16 + r16) * 32 + q * 8;
      bh[j] = *(const bf16x8*)&Bhs[cur][o];
      bl[j] = *(const bf16x8*)&Bls[cur][o];
    }
    #pragma unroll
    for (int i = 0; i < 4; ++i)
      #pragma unroll
      for (int j = 0; j < 4; ++j) {
        acc[i][j] = __builtin_amdgcn_mfma_f32_16x16x32_bf16(ah[i], bh[j], acc[i][j], 0, 0, 0);
        acc[i][j] = __builtin_amdgcn_mfma_f32_16x16x32_bf16(al[i], bh[j], acc[i][j], 0, 0, 0);
        acc[i][j] = __builtin_amdgcn_mfma_f32_16x16x32_bf16(ah[i], bl[j], acc[i][j], 0, 0, 0);
      }
    __syncthreads();
    cur ^= 1;
  }
  #pragma unroll
  for (int j = 0; j < 4; ++j) {
    int col = n0 + wn * 64 + j * 16 + r16;
    float bv = bias[col];
    #pragma unroll
    for (int i = 0; i < 4; ++i) {
      int row = m0 + wm * 64 + i * 16 + q * 4;
      #pragma unroll
      for (int t2 = 0; t2 < 4; ++t2)
        C[(size_t)(row + t2) * N + col] = gelu_f(acc[i][j][t2] + bv);
    }
  }
}

// ---- router GEMM2 + softmax + top2 -> sel; flag near-tie tokens (append to ftok) ----
__global__ void k_logits(const float* __restrict__ r, const float* __restrict__ w2,
                         const float* __restrict__ b2, const float* __restrict__ temp,
                         int* __restrict__ sel_i, float* __restrict__ sel_p,
                         int* __restrict__ flag, float* __restrict__ lg32,
                         int* __restrict__ nflag, int* __restrict__ ftok) {
  int t = blockIdx.x, tid = threadIdx.x;
  const float* rr = r + (size_t)t * RH;
  float acc[NE];
  #pragma unroll
  for (int e = 0; e < NE; ++e) acc[e] = 0.f;
  #pragma unroll
  for (int k4 = 0; k4 < 4; ++k4) {
    float4 rv4 = ((const float4*)rr)[tid * 4 + k4];
    #pragma unroll
    for (int kk = 0; kk < 4; ++kk) {
      int d = tid * 16 + k4 * 4 + kk;
      float rv = (kk == 0) ? rv4.x : (kk == 1) ? rv4.y : (kk == 2) ? rv4.z : rv4.w;
      const float4* wr = (const float4*)(w2 + (size_t)d * NE);
      float4 w0 = wr[0], w1 = wr[1];
      acc[0] += rv * w0.x; acc[1] += rv * w0.y; acc[2] += rv * w0.z; acc[3] += rv * w0.w;
      acc[4] += rv * w1.x; acc[5] += rv * w1.y; acc[6] += rv * w1.z; acc[7] += rv * w1.w;
    }
  }
  #pragma unroll
  for (int off = 32; off > 0; off >>= 1)
    #pragma unroll
    for (int e = 0; e < NE; ++e) acc[e] += __shfl_down(acc[e], off);
  __shared__ float shl[4][NE];
  int w = tid >> 6, lane = tid & 63;
  if (lane == 0) {
    #pragma unroll
    for (int e = 0; e < NE; ++e) shl[w][e] = acc[e];
  }
  __syncthreads();
  if (tid == 0) {
    float tmp = temp[0];
    float lg[NE];
    #pragma unroll
    for (int e = 0; e < NE; ++e)
      lg[e] = (shl[0][e] + shl[1][e] + shl[2][e] + shl[3][e] + b2[e]) / tmp;
    float mx = lg[0];
    for (int e = 1; e < NE; ++e) mx = fmaxf(mx, lg[e]);
    float p[NE], se = 0.f;
    for (int e = 0; e < NE; ++e) { p[e] = expf(lg[e] - mx); se += p[e]; }
    float inv = 1.f / se;
    int i1 = 0; float p1 = p[0];
    for (int e = 1; e < NE; ++e) if (p[e] > p1) { p1 = p[e]; i1 = e; }
    int i2 = -1; float p2 = -1.f;
    for (int e = 0; e < NE; ++e) if (e != i1 && p[e] > p2) { p2 = p[e]; i2 = e; }
    sel_i[t * 2] = i1; sel_i[t * 2 + 1] = i2;
    sel_p[t * 2] = p1 * inv; sel_p[t * 2 + 1] = p2 * inv;
    // flag if 2nd/3rd logit gap is within split-precision noise margin
    float a1 = -1e30f, a2 = -1e30f, a3 = -1e30f;
    for (int e = 0; e < NE; ++e) {
      float vv = lg[e];
      if (vv > a1) { a3 = a2; a2 = a1; a1 = vv; }
      else if (vv > a2) { a3 = a2; a2 = vv; }
      else if (vv > a3) a3 = vv;
    }
    int fl = (a2 - a3 < 0.01f) ? 1 : 0;
    flag[t] = fl;
    if (fl) {
      int pidx = atomicAdd(nflag, 1);
      ftok[pidx] = t;
      #pragma unroll
      for (int e = 0; e < NE; ++e) lg32[(size_t)t * NE + e] = 0.f;
    }
  }
}

// ---- parallel exact fp32 recompute of raw logits for flagged tokens (persistent loop) ----
__global__ void k_triage2(const int* __restrict__ nflag, const int* __restrict__ ftok,
                          const float* __restrict__ xh32, const float* __restrict__ W32,
                          const float* __restrict__ biasr, const float* __restrict__ w2,
                          float* __restrict__ lg32) {
  int nf = *nflag;
  __shared__ float xs[DD];
  __shared__ float sh2[4][NE];
  int tid = threadIdx.x;
  int w = tid >> 6, lane = tid & 63;
  for (int idx = blockIdx.y; idx < nf; idx += (int)gridDim.y) {
    int t = ftok[idx];
    ((float4*)xs)[tid] = ((const float4*)(xh32 + (size_t)t * DD))[tid];
    __syncthreads();
    int hh0 = blockIdx.x * 64 + w * 16;
    float acc[NE];
    #pragma unroll
    for (int e = 0; e < NE; ++e) acc[e] = 0.f;
    #pragma unroll
    for (int r = 0; r < 16; ++r) {
      int hh = hh0 + r;
      const float4* wrow = (const float4*)(W32 + (size_t)hh * DD);
      float s = 0.f;
      #pragma unroll
      for (int c = 0; c < 4; ++c) {
        float4 wv = wrow[lane + 64 * c];
        float4 xv = ((const float4*)xs)[lane + 64 * c];
        s += wv.x * xv.x + wv.y * xv.y + wv.z * xv.z + wv.w * xv.w;
      }
      #pragma unroll
      for (int off = 32; off > 0; off >>= 1) s += __shfl_down(s, off);
      if (lane == 0) {
        float r1 = gelu_f(s + biasr[hh]);
        const float* wr = w2 + (size_t)hh * NE;
        #pragma unroll
        for (int e = 0; e < NE; ++e) acc[e] += r1 * wr[e];
      }
    }
    if (lane == 0) {
      #pragma unroll
      for (int e = 0; e < NE; ++e) sh2[w][e] = acc[e];
    }
    __syncthreads();
    if (tid < NE) {
      float v = sh2[0][tid] + sh2[1][tid] + sh2[2][tid] + sh2[3][tid];
      atomicAdd(&lg32[(size_t)t * NE + tid], v);
    }
  }
}

// ---- finalize sel for flagged tokens from exact logits; count all tokens -> cnt ----
__global__ void k_gate2(const int* __restrict__ flag, const float* __restrict__ lg32,
                        const float* __restrict__ b2, const float* __restrict__ temp,
                        int* __restrict__ sel_i, float* __restrict__ sel_p,
                        int* __restrict__ cnt) {
  int t = blockIdx.x * 256 + threadIdx.x;
  if (t >= TOK) return;
  int i1, i2;
  if (flag[t]) {
    float tmp = temp[0];
    float lg[NE];
    #pragma unroll
    for (int e = 0; e < NE; ++e) lg[e] = (lg32[(size_t)t * NE + e] + b2[e]) / tmp;
    float mx = lg[0];
    for (int e = 1; e < NE; ++e) mx = fmaxf(mx, lg[e]);
    float p[NE], se = 0.f;
    for (int e = 0; e < NE; ++e) { p[e] = expf(lg[e] - mx); se += p[e]; }
    float inv = 1.f / se;
    i1 = 0; float p1 = p[0];
    for (int e = 1; e < NE; ++e) if (p[e] > p1) { p1 = p[e]; i1 = e; }
    i2 = -1; float p2 = -1.f;
    for (int e = 0; e < NE; ++e) if (e != i1 && p[e] > p2) { p2 = p[e]; i2 = e; }
    sel_i[t * 2] = i1; sel_i[t * 2 + 1] = i2;
    sel_p[t * 2] = p1 * inv; sel_p[t * 2 + 1] = p2 * inv;
  } else {
    i1 = sel_i[t * 2]; i2 = sel_i[t * 2 + 1];
  }
  atomicAdd(&cnt[i1], 1);
  atomicAdd(&cnt[i2], 1);
}

__global__ void k_offsets(const int* __restrict__ cnt, int* __restrict__ off,
                          int* __restrict__ tile_e, int* __restrict__ tile_r0,
                          int* __restrict__ ntiles) {
  if (threadIdx.x == 0) {
    int cur = 0, nt = 0;
    for (int e = 0; e < NE; ++e) {
      off[e] = cur;
      int n = (cnt[e] + 127) >> 7;
      for (int k = 0; k < n; ++k) { tile_e[nt] = e; tile_r0[nt] = cur + 128 * k; nt++; }
      cur += n * 128;
    }
    *ntiles = nt;
  }
}

__global__ void k_fill(const int* __restrict__ sel_i, const int* __restrict__ off,
                       int* __restrict__ fill, int* __restrict__ slotarr,
                       int* __restrict__ tok_of) {
  int t = blockIdx.x * 256 + threadIdx.x;
  if (t >= TOK) return;
  #pragma unroll
  for (int j = 0; j < 2; ++j) {
    int e = sel_i[2 * t + j];
    int pos = atomicAdd(&fill[e], 1);
    int s = off[e] + pos;
    slotarr[2 * t + j] = s;
    tok_of[s] = t;
  }
}

// ---- combined = w0*(sum_z pp[z][s0]+b2[e0]) + w1*(sum_z pp[z][s1]+b2[e1]); LN -> xc ----
__global__ void k_combine2(const int* __restrict__ slotarr, const int* __restrict__ sel_i,
                           const float* __restrict__ sel_p, const float* __restrict__ pairpart,
                           const float* __restrict__ e_b2, unsigned short* __restrict__ xc) {
  int t = blockIdx.x, tid = threadIdx.x;
  int s0 = slotarr[t * 2], s1 = slotarr[t * 2 + 1];
  int e0 = sel_i[t * 2], e1 = sel_i[t * 2 + 1];
  float w0 = sel_p[t * 2], w1 = sel_p[t * 2 + 1];
  float a0x = 0.f, a0y = 0.f, a0z = 0.f, a0w = 0.f;
  float a1x = 0.f, a1y = 0.f, a1z = 0.f, a1w = 0.f;
  #pragma unroll
  for (int z = 0; z < KSG2; ++z) {
    float4 u = ((const float4*)(pairpart + (size_t)z * MAXROWS * DD + (size_t)s0 * DD))[tid];
    a0x += u.x; a0y += u.y; a0z += u.z; a0w += u.w;
    float4 v = ((const float4*)(pairpart + (size_t)z * MAXROWS * DD + (size_t)s1 * DD))[tid];
    a1x += v.x; a1y += v.y; a1z += v.z; a1w += v.w;
  }
  float4 b0 = ((const float4*)(e_b2 + (size_t)e0 * DD))[tid];
  float4 b1v = ((const float4*)(e_b2 + (size_t)e1 * DD))[tid];
  float v[4];
  v[0] = w0 * (a0x + b0.x) + w1 * (a1x + b1v.x);
  v[1] = w0 * (a0y + b0.y) + w1 * (a1y + b1v.y);
  v[2] = w0 * (a0z + b0.z) + w1 * (a1z + b1v.z);
  v[3] = w0 * (a0w + b0.w) + w1 * (a1w + b1v.w);
  float s1f = v[0] + v[1] + v[2] + v[3];
  float s2f = v[0]*v[0] + v[1]*v[1] + v[2]*v[2] + v[3]*v[3];
  float mean, rstd;
  block_ln_stats(s1f, s2f, mean, rstd);
  ushort4 o;
  o.x = f2bf((v[0] - mean) * rstd); o.y = f2bf((v[1] - mean) * rstd);
  o.z = f2bf((v[2] - mean) * rstd); o.w = f2bf((v[3] - mean) * rstd);
  ((ushort4*)(xc + (size_t)t * DD))[tid] = o;
}

// ---- out = layernorm(h + sum_z c2part[z] + c_b2, o_g, o_b) ----
__global__ void k_final(const float* __restrict__ h, const float* __restrict__ c2p,
                        const float* __restrict__ cb2, const float* __restrict__ og,
                        const float* __restrict__ ob, float* __restrict__ out) {
  int t = blockIdx.x, tid = threadIdx.x;
  float4 hv = ((const float4*)(h + (size_t)t * DD))[tid];
  float ax = 0.f, ay = 0.f, az = 0.f, aw = 0.f;
  #pragma unroll
  for (int z = 0; z < KSC2; ++z) {
    float4 u = ((const float4*)(c2p + (size_t)z * TOK * DD + (size_t)t * DD))[tid];
    ax += u.x; ay += u.y; az += u.z; aw += u.w;
  }
  float4 cb = ((const float4*)cb2)[tid];
  float v[4] = {hv.x + ax + cb.x, hv.y + ay + cb.y, hv.z + az + cb.z, hv.w + aw + cb.w};
  float s1 = v[0] + v[1] + v[2] + v[3];
  float s2 = v[0]*v[0] + v[1]*v[1] + v[2]*v[2] + v[3]*v[3];
  float mean, rstd;
  block_ln_stats(s1, s2, mean, rstd);
  float4 gv = ((const float4*)og)[tid];
  float4 bv = ((const float4*)ob)[tid];
  float4 o;
  o.x = (v[0] - mean) * rstd * gv.x + bv.x;
  o.y = (v[1] - mean) * rstd * gv.y + bv.y;
  o.z = (v[2] - mean) * rstd * gv.z + bv.z;
  o.w = (v[3] - mean) * rstd * gv.w + bv.w;
  ((float4*)(out + (size_t)t * DD))[tid] = o;
}

extern "C" void kernel_launch(void* const* d_in, const int* in_sizes, int n_in,
                              void* d_out, int out_size, void* d_ws, size_t ws_size,
                              hipStream_t stream) {
  (void)in_sizes; (void)n_in; (void)out_size; (void)ws_size;
  const float* x      = (const float*)d_in[0];
  const float* r_ln_g = (const float*)d_in[1];
  const float* r_ln_b = (const float*)d_in[2];
  const float* r_w1   = (const float*)d_in[3];
  const float* r_b1   = (const float*)d_in[4];
  const float* r_w2   = (const float*)d_in[5];
  const float* r_b2   = (const float*)d_in[6];
  const float* temp   = (const float*)d_in[7];
  const float* e_ln_g = (const float*)d_in[8];
  const float* e_ln_b = (const float*)d_in[9];
  const float* e_w1   = (const float*)d_in[10];
  const float* e_b1   = (const float*)d_in[11];
  const float* e_w2   = (const float*)d_in[12];
  const float* e_b2   = (const float*)d_in[13];
  const float* c_ln_g = (const float*)d_in[14];
  const float* c_ln_b = (const float*)d_in[15];
  const float* c_w1   = (const float*)d_in[16];
  const float* c_b1   = (const float*)d_in[17];
  const float* c_w2   = (const float*)d_in[18];
  const float* c_b2   = (const float*)d_in[19];
  const float* o_ln_g = (const float*)d_in[20];
  const float* o_ln_b = (const float*)d_in[21];
  float* out = (float*)d_out;

  char* base = (char*)d_ws;
  long long cur = 0;
  auto take = [&](long long sz) { char* r = base + cur; cur += (sz + 255) & ~255LL; return r; };

  float* h      = (float*)take(8388608);            // [2048,1024] fp32
  float* xh32   = (float*)take(8388608);            // xhat fp32
  unsigned short* xhi = (unsigned short*)take(4194304); // xhat bf16 hi
  unsigned short* xlo = (unsigned short*)take(4194304); // xhat bf16 lo
  unsigned short* WrH = (unsigned short*)take(8388608); // router W1^T*g hi
  unsigned short* WrL = (unsigned short*)take(8388608);
  float* Wr32   = (float*)take(16777216);           // router W1^T*g fp32 (triage)
  float* biasr  = (float*)take(16384);
  float* ract   = (float*)take(33554432);           // gelu(router GEMM1) fp32
  int*   flag   = (int*)take(8192);
  float* lg32   = (float*)take(65536);              // exact fp32 logits (triage accum)
  int*   sel_i  = (int*)take(16384);                // [TOK][2] expert idx
  float* sel_p  = (float*)take(16384);              // [TOK][2] gate prob
  int*   cnt    = (int*)take(256);
  int*   off    = (int*)take(256);
  int*   fillc  = (int*)take(256);
  int*   tile_e = (int*)take(256);
  int*   tile_r0= (int*)take(256);
  int*   ntiles = (int*)take(256);
  int*   nflag  = (int*)take(256);
  int*   ftok   = (int*)take(TOK * 4);
  int*   slotarr= (int*)take(16384);                // [TOK][2] -> pair slot
  int*   tok_of = (int*)take(MAXROWS * 4);          // pair slot -> token
  unsigned short* We1 = (unsigned short*)take(67108864); // [8][4096,1024]
  float* be1    = (float*)take(131072);
  unsigned short* We2 = (unsigned short*)take(67108864); // [8][1024,4096]
  unsigned short* Wc1 = (unsigned short*)take(4194304);
  float* bc1    = (float*)take(8192);
  unsigned short* Wc2 = (unsigned short*)take(4194304);
  unsigned short* xc  = (unsigned short*)take(4194304);
  unsigned short* c1  = (unsigned short*)take(8388608);
  unsigned short* F1g = (unsigned short*)take((long long)MAXROWS * RH * 2);  // 40 MB
  float* pairpart = (float*)take((long long)KSG2 * MAXROWS * DD * 4);        // 84 MB fp32 partials
  // combiner split-K partials alias the dead router region (WrH/WrL/Wr32 and biasr/ract
  // are last read by k_triage2/k_logits, long before the combiner GEMMs run):
  float* c1part = (float*)WrH;    // needs 2*2048*2048*4 = 33.55 MB <= WrH+WrL+Wr32 (33.55 MB)
  float* c2part = (float*)biasr;  // needs 4*2048*1024*4 = 33.55 MB <= biasr+ract (33.57 MB)

  // prep (also zeroes bucketing state) + weight conversion
  k_prep<<<TOK, 256, 0, stream>>>(x, h, xh32, xhi, xlo, cnt, fillc, nflag, tok_of);
  k_tconv_split<<<dim3(RH/32, DD/32, 1), 256, 0, stream>>>(r_w1, r_ln_g, WrH, WrL, Wr32, DD, RH);
  k_tconv<<<dim3(RH/64, DD/64, NE), 256, 0, stream>>>(e_w1, e_ln_g, We1, DD, RH,
      (long long)DD*RH, (long long)DD, (long long)RH*DD);
  k_tconv<<<dim3(DD/64, HE/64, NE), 256, 0, stream>>>(e_w2, nullptr, We2, HE, DD,
      (long long)HE*DD, 0LL, (long long)DD*HE);
  k_tconv<<<dim3(CH/64, DD/64, 1), 256, 0, stream>>>(c_w1, c_ln_g, Wc1, DD, CH, 0LL, 0LL, 0LL);
  k_tconv<<<dim3(DD/64, CH/64, 1), 256, 0, stream>>>(c_w2, nullptr, Wc2, CH, DD, 0LL, 0LL, 0LL);
  k_foldbias<<<dim3(RH/256, 1), 256, 0, stream>>>(r_w1, r_ln_b, r_b1, biasr, DD, RH, 0LL, 0LL, 0LL, 0LL);
  k_foldbias<<<dim3(RH/256, NE), 256, 0, stream>>>(e_w1, e_ln_b, e_b1, be1, DD, RH,
      (long long)DD*RH, (long long)DD, (long long)RH, (long long)RH);
  k_foldbias<<<dim3(CH/256, 1), 256, 0, stream>>>(c_w1, c_ln_b, c_b1, bc1, DD, CH, 0LL, 0LL, 0LL, 0LL);

  // router (split precision) + top2 + near-tie parallel triage (compact grid)
  k_gemm_split<<<dim3(RH/128, TOK/128, 1), 256, 0, stream>>>(xhi, xlo, WrH, WrL, biasr, ract, RH, DD);
  k_logits<<<TOK, 256, 0, stream>>>(ract, r_w2, r_b2, temp, sel_i, sel_p, flag, lg32, nflag, ftok);
  k_triage2<<<dim3(RH/64, 32), 256, 0, stream>>>(nflag, ftok, xh32, Wr32, biasr, r_w2, lg32);
  k_gate2<<<TOK/256, 256, 0, stream>>>(flag, lg32, r_b2, temp, sel_i, sel_p, cnt);

  // bucket (token,expert) pairs by expert
  k_offsets<<<1, 64, 0, stream>>>(cnt, off, tile_e, tile_r0, ntiles);
  k_fill<<<TOK/256, 256, 0, stream>>>(sel_i, off, fillc, slotarr, tok_of);

  // sparse grouped expert FFN (only selected pairs); GEMM2 split-K=4 for occupancy
  k_gemm_g1<<<dim3(RH/128, MAXTILE), 256, 0, stream>>>(xhi, We1, be1, F1g,
      tok_of, tile_e, tile_r0, ntiles);
  k_gemm_g2<<<dim3(DD/128, MAXTILE, KSG2), 256, 0, stream>>>(F1g, We2, pairpart,
      tile_e, tile_r0, ntiles);

  // combine (reduces split-K partials) + combiner MLP (split-K) + residual/output LN
  k_combine2<<<TOK, 256, 0, stream>>>(slotarr, sel_i, sel_p, pairpart, e_b2, xc);
  k_gemm_sk<<<dim3(CH/128, TOK/128, KSC1), 256, 0, stream>>>(xc, Wc1, c1part, CH, DD,
      DD/KSC1, (long long)TOK * CH);
  k_redg<<<(TOK * CH) / 1024, 256, 0, stream>>>(c1part, bc1, c1, CH, (long long)TOK * CH, KSC1);
  k_gemm_sk<<<dim3(DD/128, TOK/128, KSC2), 256, 0, stream>>>(c1, Wc2, c2part, DD, CH,
      CH/KSC2, (long long)TOK * DD);
  k_final<<<TOK, 256, 0, stream>>>(h, c2part, c_b2, o_ln_g, o_ln_b, out);
}

// Round 3
// 1050.098 us; speedup vs baseline: 1.0478x; 1.0478x over previous
//
#include <hip/hip_runtime.h>
#include <stdint.h>

// Problem dims
#define TOK 2048   // B*S
#define DD  1024   // D
#define RH  4096   // router hidden H
#define HE  4096   // expert hidden
#define NE  8      // experts
#define CH  2048   // combiner hidden 2D
#define MAXTILE 40    // max 128-row tiles across experts: 4096/128 + 7 = 39
#define MAXROWS 5120  // 4096 pairs + 8*127 pad, rounded up
#define KSC2 2     // split-K for combiner GEMM2 (K=2048 -> 1024 each)

using bf16x8 = __attribute__((ext_vector_type(8))) short;
using f32x4  = __attribute__((ext_vector_type(4))) float;

__device__ __forceinline__ unsigned short f2bf(float f) {
  union { float f; uint32_t u; } v; v.f = f;
  uint32_t r = (v.u + 0x7fffu + ((v.u >> 16) & 1u)) >> 16;
  return (unsigned short)r;
}
__device__ __forceinline__ float bf2f(unsigned short h) {
  union { uint32_t u; float f; } v; v.u = ((uint32_t)h) << 16;
  return v.f;
}
__device__ __forceinline__ float gelu_f(float x) {
  return 0.5f * x * (1.0f + erff(x * 0.70710678118654752440f));
}

// async global->LDS, 16B per lane; LDS dest = wave-uniform base + lane*16
#define GLD(SRC, DST) __builtin_amdgcn_global_load_lds( \
    (const __attribute__((address_space(1))) uint32_t*)(const void*)(SRC), \
    (__attribute__((address_space(3))) uint32_t*)(void*)(DST), 16, 0, 0)

// block (256 threads) LN stats over 1024 values (4 per thread already summed)
__device__ __forceinline__ void block_ln_stats(float s1, float s2, float& mean, float& rstd) {
  #pragma unroll
  for (int off = 32; off > 0; off >>= 1) {
    s1 += __shfl_down(s1, off);
    s2 += __shfl_down(s2, off);
  }
  __shared__ float sh[8];
  int tid = threadIdx.x;
  if ((tid & 63) == 0) { sh[tid >> 6] = s1; sh[4 + (tid >> 6)] = s2; }
  __syncthreads();
  float t1 = sh[0] + sh[1] + sh[2] + sh[3];
  float t2 = sh[4] + sh[5] + sh[6] + sh[7];
  mean = t1 * (1.0f / 1024.0f);
  float var = t2 * (1.0f / 1024.0f) - mean * mean;
  rstd = rsqrtf(var + 1e-5f);
}

// ---- h = x + pos_encoding; shared LN stats; xhat fp32 + bf16 hi/lo ----
// also zeroes bucketing state (folds memsets); paired sincosf halves trig cost
__global__ void k_prep(const float* __restrict__ x, float* __restrict__ h,
                       float* __restrict__ xh32, unsigned short* __restrict__ xhi,
                       unsigned short* __restrict__ xlo, int* __restrict__ cnt,
                       int* __restrict__ fillc, int* __restrict__ nflag,
                       int* __restrict__ tok_of) {
  int t = blockIdx.x;
  int s = t & 1023;
  int tid = threadIdx.x;
  float4 xv = ((const float4*)(x + (size_t)t * DD))[tid];
  float v[4]; float s1 = 0.f, s2 = 0.f;
  #pragma unroll
  for (int kp = 0; kp < 2; ++kp) {
    float i2 = (float)(tid * 4 + kp * 2);   // even d shared by (sin,cos) pair
    float div = expf(-9.2103403719761836f * i2 * (1.0f / 1024.0f));
    float ang = (float)s * div;
    float sn, cs;
    sincosf(ang, &sn, &cs);
    float xe = (kp == 0) ? xv.x : xv.z;
    float xo = (kp == 0) ? xv.y : xv.w;
    v[kp * 2] = xe + sn; v[kp * 2 + 1] = xo + cs;
  }
  #pragma unroll
  for (int k = 0; k < 4; ++k) { s1 += v[k]; s2 += v[k] * v[k]; }
  float mean, rstd;
  block_ln_stats(s1, s2, mean, rstd);
  float4 ho; ho.x = v[0]; ho.y = v[1]; ho.z = v[2]; ho.w = v[3];
  ((float4*)(h + (size_t)t * DD))[tid] = ho;
  float xn[4]; unsigned short hh[4], ll[4];
  #pragma unroll
  for (int k = 0; k < 4; ++k) {
    xn[k] = (v[k] - mean) * rstd;
    hh[k] = f2bf(xn[k]);
    ll[k] = f2bf(xn[k] - bf2f(hh[k]));
  }
  float4 xo4; xo4.x = xn[0]; xo4.y = xn[1]; xo4.z = xn[2]; xo4.w = xn[3];
  ((float4*)(xh32 + (size_t)t * DD))[tid] = xo4;
  ushort4 h4; h4.x = hh[0]; h4.y = hh[1]; h4.z = hh[2]; h4.w = hh[3];
  ((ushort4*)(xhi + (size_t)t * DD))[tid] = h4;
  ushort4 l4; l4.x = ll[0]; l4.y = ll[1]; l4.z = ll[2]; l4.w = ll[3];
  ((ushort4*)(xlo + (size_t)t * DD))[tid] = l4;
  if (t == 0) {
    for (int i = tid; i < MAXROWS; i += 256) tok_of[i] = 0;
    if (tid < NE) { cnt[tid] = 0; fillc[tid] = 0; }
    if (tid == 0) nflag[0] = 0;
  }
}

// ---- transpose+convert weights: in fp32 [D,N] (opt row-scale g[D]) -> out bf16 [N,D] ----
__global__ void k_tconv(const float* __restrict__ in, const float* __restrict__ g,
                        unsigned short* __restrict__ out, int D, int N,
                        long long in_bs, long long g_bs, long long out_bs) {
  __shared__ float tile[64][65];
  int e = blockIdx.z;
  const float* inb = in + (size_t)e * in_bs;
  unsigned short* outb = out + (size_t)e * out_bs;
  int n0 = blockIdx.x * 64, d0 = blockIdx.y * 64;
  int c4 = threadIdx.x & 15;   // 16 float4 per 64-wide row
  int r0 = threadIdx.x >> 4;   // 16 rows per pass
  #pragma unroll
  for (int rr = 0; rr < 4; ++rr) {
    int dl = r0 + rr * 16;
    float4 v = *(const float4*)(inb + (size_t)(d0 + dl) * N + n0 + c4 * 4);
    if (g) {
      float gv = g[(size_t)e * g_bs + d0 + dl];
      v.x *= gv; v.y *= gv; v.z *= gv; v.w *= gv;
    }
    tile[dl][c4 * 4 + 0] = v.x; tile[dl][c4 * 4 + 1] = v.y;
    tile[dl][c4 * 4 + 2] = v.z; tile[dl][c4 * 4 + 3] = v.w;
  }
  __syncthreads();
  int q = threadIdx.x & 15;
  int nb = threadIdx.x >> 4;
  #pragma unroll
  for (int rr = 0; rr < 4; ++rr) {
    int nl = nb + rr * 16;
    ushort4 o;
    o.x = f2bf(tile[q * 4 + 0][nl]); o.y = f2bf(tile[q * 4 + 1][nl]);
    o.z = f2bf(tile[q * 4 + 2][nl]); o.w = f2bf(tile[q * 4 + 3][nl]);
    *(ushort4*)(outb + (size_t)(n0 + nl) * D + d0 + q * 4) = o;
  }
}

// router variant: writes bf16 hi, bf16 lo, and fp32 transposed copies
__global__ void k_tconv_split(const float* __restrict__ in, const float* __restrict__ g,
                              unsigned short* __restrict__ oh, unsigned short* __restrict__ ol,
                              float* __restrict__ o32, int D, int N) {
  __shared__ float tile[32][33];
  int n0 = blockIdx.x * 32, d0 = blockIdx.y * 32;
  int tn = threadIdx.x & 31, tr = threadIdx.x >> 5;
  #pragma unroll
  for (int rr = 0; rr < 4; ++rr) {
    int dl = tr + rr * 8;
    float v = in[(size_t)(d0 + dl) * N + n0 + tn];
    if (g) v *= g[d0 + dl];
    tile[dl][tn] = v;
  }
  __syncthreads();
  #pragma unroll
  for (int rr = 0; rr < 4; ++rr) {
    int nl = tr + rr * 8;
    float v = tile[tn][nl];
    size_t off = (size_t)(n0 + nl) * D + d0 + tn;
    unsigned short hi = f2bf(v);
    oh[off] = hi;
    ol[off] = f2bf(v - bf2f(hi));
    o32[off] = v;
  }
}

// ---- bias fold: out[n] = b1[n] + sum_d lnb[d]*w[d,n]  (skips w reads if lnb[d]==0) ----
__global__ void k_foldbias(const float* __restrict__ w, const float* __restrict__ lnb,
                           const float* __restrict__ b1, float* __restrict__ outb,
                           int D, int N, long long w_bs, long long lnb_bs,
                           long long b_bs, long long o_bs) {
  int e = blockIdx.y;
  int n = blockIdx.x * 256 + threadIdx.x;
  const float* wb = w + (size_t)e * w_bs;
  const float* lb = lnb + (size_t)e * lnb_bs;
  float acc = b1[(size_t)e * b_bs + n];
  for (int d = 0; d < D; ++d) {
    float l = lb[d];
    if (l != 0.f) acc += l * wb[(size_t)d * N + n];
  }
  outb[(size_t)e * o_bs + n] = acc;
}

// ---- dense 128x64-tile GEMM: C = A[M,K] @ Bt[N,Kslice]^T (+bias, opt gelu) ----
// single-buffer 2-barrier loop; kz selects K slice for fp32-partial output
template <int DO_GELU, int OUT_BF16>
__global__ __launch_bounds__(256)
void k_gemm_n64(const unsigned short* __restrict__ A, const unsigned short* __restrict__ B,
                const float* __restrict__ bias, void* __restrict__ Cv, int N, int K,
                int kslice, long long c_slice) {
  __shared__ __align__(16) unsigned short As[128 * 32];
  __shared__ __align__(16) unsigned short Bs[64 * 32];
  const int tid = threadIdx.x;
  const int w = tid >> 6, lane = tid & 63;
  const int q = lane >> 4, r16 = lane & 15;
  const int kz = blockIdx.z;
  const int n0 = blockIdx.x * 64, m0 = blockIdx.y * 128;
  f32x4 acc[4][2];
  #pragma unroll
  for (int i = 0; i < 4; ++i)
    #pragma unroll
    for (int j = 0; j < 2; ++j) acc[i][j] = (f32x4){0.f, 0.f, 0.f, 0.f};
  const int srow = w * 32 + (lane >> 2);
  const int bsrow = (w < 2) ? srow : 0;
  const int scol = (lane & 3) * 8;
  const unsigned short* a_src = A + (size_t)(m0 + srow) * K + scol + (size_t)kz * kslice;
  const unsigned short* b_src = B + (size_t)(n0 + bsrow) * K + scol + (size_t)kz * kslice;
  unsigned short* a_dst = &As[w * 1024];
  unsigned short* b_dst = &Bs[(w & 1) * 1024];
  const int wm = w >> 1, wn = w & 1;
  for (int kt = 0; kt < kslice; kt += 32) {
    GLD(a_src + kt, a_dst);
    GLD(a_src + kt + (size_t)16 * K, a_dst + 512);
    if (w < 2) {
      GLD(b_src + kt, b_dst);
      GLD(b_src + kt + (size_t)16 * K, b_dst + 512);
    }
    __syncthreads();
    bf16x8 af[4], bfv[2];
    #pragma unroll
    for (int i = 0; i < 4; ++i)
      af[i] = *(const bf16x8*)&As[(wm * 64 + i * 16 + r16) * 32 + q * 8];
    #pragma unroll
    for (int j = 0; j < 2; ++j)
      bfv[j] = *(const bf16x8*)&Bs[(wn * 32 + j * 16 + r16) * 32 + q * 8];
    #pragma unroll
    for (int i = 0; i < 4; ++i)
      #pragma unroll
      for (int j = 0; j < 2; ++j)
        acc[i][j] = __builtin_amdgcn_mfma_f32_16x16x32_bf16(af[i], bfv[j], acc[i][j], 0, 0, 0);
    __syncthreads();
  }
  #pragma unroll
  for (int j = 0; j < 2; ++j) {
    int col = n0 + wn * 32 + j * 16 + r16;
    float bv = bias ? bias[col] : 0.f;
    #pragma unroll
    for (int i = 0; i < 4; ++i) {
      int row = m0 + wm * 64 + i * 16 + q * 4;
      #pragma unroll
      for (int t2 = 0; t2 < 4; ++t2) {
        float vv = acc[i][j][t2] + bv;
        if (DO_GELU) vv = gelu_f(vv);
        if (OUT_BF16) ((unsigned short*)Cv)[(size_t)(row + t2) * N + col] = f2bf(vv);
        else ((float*)Cv)[(size_t)kz * c_slice + (size_t)(row + t2) * N + col] = vv;
      }
    }
  }
}

// ---- grouped expert GEMM1 (128x128): gathered tokens -> gelu -> F1g [slot][RH] ----
__global__ __launch_bounds__(256)
void k_gemm_g1(const unsigned short* __restrict__ A, const unsigned short* __restrict__ W,
               const float* __restrict__ bias, unsigned short* __restrict__ C,
               const int* __restrict__ tok_of, const int* __restrict__ tile_e,
               const int* __restrict__ tile_r0, const int* __restrict__ ntiles) {
  if ((int)blockIdx.y >= *ntiles) return;
  __shared__ __align__(16) unsigned short As[128 * 32];
  __shared__ __align__(16) unsigned short Bs[128 * 32];
  const int tid = threadIdx.x;
  const int w = tid >> 6, lane = tid & 63;
  const int q = lane >> 4, r16 = lane & 15;
  const int e = tile_e[blockIdx.y];
  const int row0 = tile_r0[blockIdx.y];
  const int n0 = blockIdx.x * 128;
  f32x4 acc[4][4];
  #pragma unroll
  for (int i = 0; i < 4; ++i)
    #pragma unroll
    for (int j = 0; j < 4; ++j) acc[i][j] = (f32x4){0.f, 0.f, 0.f, 0.f};
  const int srow = w * 32 + (lane >> 2);
  const int scol = (lane & 3) * 8;
  const int t0 = tok_of[row0 + srow];
  const int t1 = tok_of[row0 + srow + 16];
  const unsigned short* a_src0 = A + (size_t)t0 * DD + scol;
  const unsigned short* a_src1 = A + (size_t)t1 * DD + scol;
  const unsigned short* b_src = W + (size_t)e * RH * DD + (size_t)(n0 + srow) * DD + scol;
  unsigned short* a_dst = &As[w * 1024];
  unsigned short* b_dst = &Bs[w * 1024];
  const int wm = w >> 1, wn = w & 1;
  for (int kt = 0; kt < DD; kt += 32) {
    GLD(a_src0 + kt, a_dst);
    GLD(a_src1 + kt, a_dst + 512);
    GLD(b_src + kt, b_dst);
    GLD(b_src + kt + (size_t)16 * DD, b_dst + 512);
    __syncthreads();
    bf16x8 af[4], bfv[4];
    #pragma unroll
    for (int i = 0; i < 4; ++i)
      af[i] = *(const bf16x8*)&As[(wm * 64 + i * 16 + r16) * 32 + q * 8];
    #pragma unroll
    for (int j = 0; j < 4; ++j)
      bfv[j] = *(const bf16x8*)&Bs[(wn * 64 + j * 16 + r16) * 32 + q * 8];
    #pragma unroll
    for (int i = 0; i < 4; ++i)
      #pragma unroll
      for (int j = 0; j < 4; ++j)
        acc[i][j] = __builtin_amdgcn_mfma_f32_16x16x32_bf16(af[i], bfv[j], acc[i][j], 0, 0, 0);
    __syncthreads();
  }
  #pragma unroll
  for (int j = 0; j < 4; ++j) {
    int col = n0 + wn * 64 + j * 16 + r16;
    float bv = bias[(size_t)e * RH + col];
    #pragma unroll
    for (int i = 0; i < 4; ++i) {
      int row = row0 + wm * 64 + i * 16 + q * 4;
      #pragma unroll
      for (int t2 = 0; t2 < 4; ++t2)
        C[(size_t)(row + t2) * RH + col] = f2bf(gelu_f(acc[i][j][t2] + bv));
    }
  }
}

// ---- grouped expert GEMM2 (128x64): F1g [slot][HE] @ We2[e]^T -> bf16 pairout direct ----
__global__ __launch_bounds__(256)
void k_gemm_g2n(const unsigned short* __restrict__ A, const unsigned short* __restrict__ W,
                unsigned short* __restrict__ C, const int* __restrict__ tile_e,
                const int* __restrict__ tile_r0, const int* __restrict__ ntiles) {
  if ((int)blockIdx.y >= *ntiles) return;
  __shared__ __align__(16) unsigned short As[128 * 32];
  __shared__ __align__(16) unsigned short Bs[64 * 32];
  const int tid = threadIdx.x;
  const int w = tid >> 6, lane = tid & 63;
  const int q = lane >> 4, r16 = lane & 15;
  const int e = tile_e[blockIdx.y];
  const int row0 = tile_r0[blockIdx.y];
  const int n0 = blockIdx.x * 64;
  f32x4 acc[4][2];
  #pragma unroll
  for (int i = 0; i < 4; ++i)
    #pragma unroll
    for (int j = 0; j < 2; ++j) acc[i][j] = (f32x4){0.f, 0.f, 0.f, 0.f};
  const int srow = w * 32 + (lane >> 2);
  const int bsrow = (w < 2) ? srow : 0;
  const int scol = (lane & 3) * 8;
  const unsigned short* a_src = A + (size_t)(row0 + srow) * HE + scol;
  const unsigned short* b_src = W + (size_t)e * DD * HE + (size_t)(n0 + bsrow) * HE + scol;
  unsigned short* a_dst = &As[w * 1024];
  unsigned short* b_dst = &Bs[(w & 1) * 1024];
  const int wm = w >> 1, wn = w & 1;
  for (int kt = 0; kt < HE; kt += 32) {
    GLD(a_src + kt, a_dst);
    GLD(a_src + kt + (size_t)16 * HE, a_dst + 512);
    if (w < 2) {
      GLD(b_src + kt, b_dst);
      GLD(b_src + kt + (size_t)16 * HE, b_dst + 512);
    }
    __syncthreads();
    bf16x8 af[4], bfv[2];
    #pragma unroll
    for (int i = 0; i < 4; ++i)
      af[i] = *(const bf16x8*)&As[(wm * 64 + i * 16 + r16) * 32 + q * 8];
    #pragma unroll
    for (int j = 0; j < 2; ++j)
      bfv[j] = *(const bf16x8*)&Bs[(wn * 32 + j * 16 + r16) * 32 + q * 8];
    #pragma unroll
    for (int i = 0; i < 4; ++i)
      #pragma unroll
      for (int j = 0; j < 2; ++j)
        acc[i][j] = __builtin_amdgcn_mfma_f32_16x16x32_bf16(af[i], bfv[j], acc[i][j], 0, 0, 0);
    __syncthreads();
  }
  #pragma unroll
  for (int j = 0; j < 2; ++j) {
    int col = n0 + wn * 32 + j * 16 + r16;
    #pragma unroll
    for (int i = 0; i < 4; ++i) {
      int row = row0 + wm * 64 + i * 16 + q * 4;
      #pragma unroll
      for (int t2 = 0; t2 < 4; ++t2)
        C[(size_t)(row + t2) * DD + col] = f2bf(acc[i][j][t2]);
    }
  }
}

// ---- split-precision router GEMM1 + FUSED router GEMM2 partial logits ----
// (Ah+Al)@(Bh+Bl)^T, 3 MFMA per tile, gelu; then per-block reduce over its 128 cols
// against w2 -> lgp[colTile][TOK][8] fp32 partials (no ract round-trip)
__global__ __launch_bounds__(256)
void k_gemm_split(const unsigned short* __restrict__ Ah, const unsigned short* __restrict__ Al,
                  const unsigned short* __restrict__ Bh, const unsigned short* __restrict__ Bl,
                  const float* __restrict__ bias, const float* __restrict__ w2,
                  float* __restrict__ lgp, int K) {
  __shared__ __align__(16) unsigned short Ahs[128 * 32];
  __shared__ __align__(16) unsigned short Als[128 * 32];
  __shared__ __align__(16) unsigned short Bhs[128 * 32];
  __shared__ __align__(16) unsigned short Bls[128 * 32];
  const int tid = threadIdx.x;
  const int w = tid >> 6, lane = tid & 63;
  const int q = lane >> 4, r16 = lane & 15;
  const int n0 = blockIdx.x * 128, m0 = blockIdx.y * 128;
  f32x4 acc[4][4];
  #pragma unroll
  for (int i = 0; i < 4; ++i)
    #pragma unroll
    for (int j = 0; j < 4; ++j) acc[i][j] = (f32x4){0.f, 0.f, 0.f, 0.f};
  const int srow = w * 32 + (lane >> 2);
  const int scol = (lane & 3) * 8;
  const unsigned short* ah_src = Ah + (size_t)(m0 + srow) * K + scol;
  const unsigned short* al_src = Al + (size_t)(m0 + srow) * K + scol;
  const unsigned short* bh_src = Bh + (size_t)(n0 + srow) * K + scol;
  const unsigned short* bl_src = Bl + (size_t)(n0 + srow) * K + scol;
  const int wm = w >> 1, wn = w & 1;
  for (int kt = 0; kt < K; kt += 32) {
    GLD(ah_src + kt, &Ahs[w * 1024]);
    GLD(ah_src + kt + (size_t)16 * K, &Ahs[w * 1024 + 512]);
    GLD(al_src + kt, &Als[w * 1024]);
    GLD(al_src + kt + (size_t)16 * K, &Als[w * 1024 + 512]);
    GLD(bh_src + kt, &Bhs[w * 1024]);
    GLD(bh_src + kt + (size_t)16 * K, &Bhs[w * 1024 + 512]);
    GLD(bl_src + kt, &Bls[w * 1024]);
    GLD(bl_src + kt + (size_t)16 * K, &Bls[w * 1024 + 512]);
    __syncthreads();
    bf16x8 ah[4], al[4], bh[4], bl[4];
    #pragma unroll
    for (int i = 0; i < 4; ++i) {
      int o = (wm * 64 + i * 16 + r16) * 32 + q * 8;
      ah[i] = *(const bf16x8*)&Ahs[o];
      al[i] = *(const bf16x8*)&Als[o];
    }
    #pragma unroll
    for (int j = 0; j < 4; ++j) {
      int o = (wn * 64 + j * 16 + r16) * 32 + q * 8;
      bh[j] = *(const bf16x8*)&Bhs[o];
      bl[j] = *(const bf16x8*)&Bls[o];
    }
    #pragma unroll
    for (int i = 0; i < 4; ++i)
      #pragma unroll
      for (int j = 0; j < 4; ++j) {
        acc[i][j] = __builtin_amdgcn_mfma_f32_16x16x32_bf16(ah[i], bh[j], acc[i][j], 0, 0, 0);
        acc[i][j] = __builtin_amdgcn_mfma_f32_16x16x32_bf16(al[i], bh[j], acc[i][j], 0, 0, 0);
        acc[i][j] = __builtin_amdgcn_mfma_f32_16x16x32_bf16(ah[i], bl[j], acc[i][j], 0, 0, 0);
      }
    __syncthreads();
  }
  // fused epilogue: r = gelu(acc+bias); partial logits over this block's 128 cols
  float w2v[4][8], bv[4];
  #pragma unroll
  for (int j = 0; j < 4; ++j) {
    int col = n0 + wn * 64 + j * 16 + r16;
    bv[j] = bias[col];
    const float4* wr = (const float4*)(w2 + (size_t)col * 8);
    float4 u = wr[0], v2 = wr[1];
    w2v[j][0] = u.x;  w2v[j][1] = u.y;  w2v[j][2] = u.z;  w2v[j][3] = u.w;
    w2v[j][4] = v2.x; w2v[j][5] = v2.y; w2v[j][6] = v2.z; w2v[j][7] = v2.w;
  }
  float* plog = (float*)Ahs;   // reuse LDS: 128 rows x 8 experts fp32 = 4 KB
  #pragma unroll
  for (int idx = 0; idx < 4; ++idx) plog[idx * 256 + tid] = 0.f;
  __syncthreads();
  #pragma unroll
  for (int i = 0; i < 4; ++i)
    #pragma unroll
    for (int t2 = 0; t2 < 4; ++t2) {
      int rloc = wm * 64 + i * 16 + q * 4 + t2;
      float a8[8];
      #pragma unroll
      for (int e2 = 0; e2 < 8; ++e2) a8[e2] = 0.f;
      #pragma unroll
      for (int j = 0; j < 4; ++j) {
        float v = gelu_f(acc[i][j][t2] + bv[j]);
        #pragma unroll
        for (int e2 = 0; e2 < 8; ++e2) a8[e2] += v * w2v[j][e2];
      }
      #pragma unroll
      for (int off = 8; off > 0; off >>= 1)
        #pragma unroll
        for (int e2 = 0; e2 < 8; ++e2) a8[e2] += __shfl_down(a8[e2], off, 16);
      if (r16 == 0) {
        #pragma unroll
        for (int e2 = 0; e2 < 8; ++e2) atomicAdd(&plog[rloc * 8 + e2], a8[e2]);
      }
    }
  __syncthreads();
  float4* dst = (float4*)(lgp + ((size_t)blockIdx.x * TOK + m0) * 8);
  dst[tid] = ((float4*)plog)[tid];
}

// ---- reduce logit partials + softmax + top2 -> sel; flag near-tie tokens ----
__global__ void k_gate1(const float* __restrict__ lgp, const float* __restrict__ b2,
                        const float* __restrict__ temp, int* __restrict__ sel_i,
                        float* __restrict__ sel_p, int* __restrict__ flag,
                        float* __restrict__ lg32, int* __restrict__ nflag,
                        int* __restrict__ ftok) {
  int t = blockIdx.x * 256 + threadIdx.x;
  if (t >= TOK) return;
  float s8[NE];
  #pragma unroll
  for (int e = 0; e < NE; ++e) s8[e] = 0.f;
  for (int c = 0; c < RH / 128; ++c) {
    const float4* p = (const float4*)(lgp + ((size_t)c * TOK + t) * 8);
    float4 u = p[0], v = p[1];
    s8[0] += u.x; s8[1] += u.y; s8[2] += u.z; s8[3] += u.w;
    s8[4] += v.x; s8[5] += v.y; s8[6] += v.z; s8[7] += v.w;
  }
  float tmp = temp[0];
  float lg[NE];
  #pragma unroll
  for (int e = 0; e < NE; ++e) lg[e] = (s8[e] + b2[e]) / tmp;
  float mx = lg[0];
  for (int e = 1; e < NE; ++e) mx = fmaxf(mx, lg[e]);
  float p[NE], se = 0.f;
  for (int e = 0; e < NE; ++e) { p[e] = expf(lg[e] - mx); se += p[e]; }
  float inv = 1.f / se;
  int i1 = 0; float p1 = p[0];
  for (int e = 1; e < NE; ++e) if (p[e] > p1) { p1 = p[e]; i1 = e; }
  int i2 = -1; float p2 = -1.f;
  for (int e = 0; e < NE; ++e) if (e != i1 && p[e] > p2) { p2 = p[e]; i2 = e; }
  sel_i[t * 2] = i1; sel_i[t * 2 + 1] = i2;
  sel_p[t * 2] = p1 * inv; sel_p[t * 2 + 1] = p2 * inv;
  // flag if 2nd/3rd logit gap is within split-precision noise margin
  float a1 = -1e30f, a2 = -1e30f, a3 = -1e30f;
  for (int e = 0; e < NE; ++e) {
    float vv = lg[e];
    if (vv > a1) { a3 = a2; a2 = a1; a1 = vv; }
    else if (vv > a2) { a3 = a2; a2 = vv; }
    else if (vv > a3) a3 = vv;
  }
  int fl = (a2 - a3 < 0.01f) ? 1 : 0;
  flag[t] = fl;
  if (fl) {
    int pidx = atomicAdd(nflag, 1);
    ftok[pidx] = t;
    #pragma unroll
    for (int e = 0; e < NE; ++e) lg32[(size_t)t * NE + e] = 0.f;
  }
}

// ---- parallel exact fp32 recompute of raw logits for flagged tokens (persistent loop) ----
__global__ void k_triage2(const int* __restrict__ nflag, const int* __restrict__ ftok,
                          const float* __restrict__ xh32, const float* __restrict__ W32,
                          const float* __restrict__ biasr, const float* __restrict__ w2,
                          float* __restrict__ lg32) {
  int nf = *nflag;
  __shared__ float xs[DD];
  __shared__ float sh2[4][NE];
  int tid = threadIdx.x;
  int w = tid >> 6, lane = tid & 63;
  for (int idx = blockIdx.y; idx < nf; idx += (int)gridDim.y) {
    int t = ftok[idx];
    ((float4*)xs)[tid] = ((const float4*)(xh32 + (size_t)t * DD))[tid];
    __syncthreads();
    int hh0 = blockIdx.x * 64 + w * 16;
    float acc[NE];
    #pragma unroll
    for (int e = 0; e < NE; ++e) acc[e] = 0.f;
    #pragma unroll
    for (int r = 0; r < 16; ++r) {
      int hh = hh0 + r;
      const float4* wrow = (const float4*)(W32 + (size_t)hh * DD);
      float s = 0.f;
      #pragma unroll
      for (int c = 0; c < 4; ++c) {
        float4 wv = wrow[lane + 64 * c];
        float4 xv = ((const float4*)xs)[lane + 64 * c];
        s += wv.x * xv.x + wv.y * xv.y + wv.z * xv.z + wv.w * xv.w;
      }
      #pragma unroll
      for (int off = 32; off > 0; off >>= 1) s += __shfl_down(s, off);
      if (lane == 0) {
        float r1 = gelu_f(s + biasr[hh]);
        const float* wr = w2 + (size_t)hh * NE;
        #pragma unroll
        for (int e = 0; e < NE; ++e) acc[e] += r1 * wr[e];
      }
    }
    if (lane == 0) {
      #pragma unroll
      for (int e = 0; e < NE; ++e) sh2[w][e] = acc[e];
    }
    __syncthreads();
    if (tid < NE) {
      float v = sh2[0][tid] + sh2[1][tid] + sh2[2][tid] + sh2[3][tid];
      atomicAdd(&lg32[(size_t)t * NE + tid], v);
    }
    __syncthreads();
  }
}

// ---- finalize sel for flagged tokens from exact logits; count all tokens -> cnt ----
__global__ void k_gate2(const int* __restrict__ flag, const float* __restrict__ lg32,
                        const float* __restrict__ b2, const float* __restrict__ temp,
                        int* __restrict__ sel_i, float* __restrict__ sel_p,
                        int* __restrict__ cnt) {
  int t = blockIdx.x * 256 + threadIdx.x;
  if (t >= TOK) return;
  int i1, i2;
  if (flag[t]) {
    float tmp = temp[0];
    float lg[NE];
    #pragma unroll
    for (int e = 0; e < NE; ++e) lg[e] = (lg32[(size_t)t * NE + e] + b2[e]) / tmp;
    float mx = lg[0];
    for (int e = 1; e < NE; ++e) mx = fmaxf(mx, lg[e]);
    float p[NE], se = 0.f;
    for (int e = 0; e < NE; ++e) { p[e] = expf(lg[e] - mx); se += p[e]; }
    float inv = 1.f / se;
    i1 = 0; float p1 = p[0];
    for (int e = 1; e < NE; ++e) if (p[e] > p1) { p1 = p[e]; i1 = e; }
    i2 = -1; float p2 = -1.f;
    for (int e = 0; e < NE; ++e) if (e != i1 && p[e] > p2) { p2 = p[e]; i2 = e; }
    sel_i[t * 2] = i1; sel_i[t * 2 + 1] = i2;
    sel_p[t * 2] = p1 * inv; sel_p[t * 2 + 1] = p2 * inv;
  } else {
    i1 = sel_i[t * 2]; i2 = sel_i[t * 2 + 1];
  }
  atomicAdd(&cnt[i1], 1);
  atomicAdd(&cnt[i2], 1);
}

__global__ void k_offsets(const int* __restrict__ cnt, int* __restrict__ off,
                          int* __restrict__ tile_e, int* __restrict__ tile_r0,
                          int* __restrict__ ntiles) {
  if (threadIdx.x == 0) {
    int cur = 0, nt = 0;
    for (int e = 0; e < NE; ++e) {
      off[e] = cur;
      int n = (cnt[e] + 127) >> 7;
      for (int k = 0; k < n; ++k) { tile_e[nt] = e; tile_r0[nt] = cur + 128 * k; nt++; }
      cur += n * 128;
    }
    *ntiles = nt;
  }
}

__global__ void k_fill(const int* __restrict__ sel_i, const int* __restrict__ off,
                       int* __restrict__ fill, int* __restrict__ slotarr,
                       int* __restrict__ tok_of) {
  int t = blockIdx.x * 256 + threadIdx.x;
  if (t >= TOK) return;
  #pragma unroll
  for (int j = 0; j < 2; ++j) {
    int e = sel_i[2 * t + j];
    int pos = atomicAdd(&fill[e], 1);
    int s = off[e] + pos;
    slotarr[2 * t + j] = s;
    tok_of[s] = t;
  }
}

// ---- combined = w0*(pairout[s0]+b2[e0]) + w1*(pairout[s1]+b2[e1]); LN -> xc ----
__global__ void k_combine2(const int* __restrict__ slotarr, const int* __restrict__ sel_i,
                           const float* __restrict__ sel_p, const unsigned short* __restrict__ pairout,
                           const float* __restrict__ e_b2, unsigned short* __restrict__ xc) {
  int t = blockIdx.x, tid = threadIdx.x;
  int s0 = slotarr[t * 2], s1 = slotarr[t * 2 + 1];
  int e0 = sel_i[t * 2], e1 = sel_i[t * 2 + 1];
  float w0 = sel_p[t * 2], w1 = sel_p[t * 2 + 1];
  ushort4 u0 = ((const ushort4*)(pairout + (size_t)s0 * DD))[tid];
  ushort4 u1 = ((const ushort4*)(pairout + (size_t)s1 * DD))[tid];
  float4 b0 = ((const float4*)(e_b2 + (size_t)e0 * DD))[tid];
  float4 b1v = ((const float4*)(e_b2 + (size_t)e1 * DD))[tid];
  float v[4];
  v[0] = w0 * (bf2f(u0.x) + b0.x) + w1 * (bf2f(u1.x) + b1v.x);
  v[1] = w0 * (bf2f(u0.y) + b0.y) + w1 * (bf2f(u1.y) + b1v.y);
  v[2] = w0 * (bf2f(u0.z) + b0.z) + w1 * (bf2f(u1.z) + b1v.z);
  v[3] = w0 * (bf2f(u0.w) + b0.w) + w1 * (bf2f(u1.w) + b1v.w);
  float s1f = v[0] + v[1] + v[2] + v[3];
  float s2f = v[0]*v[0] + v[1]*v[1] + v[2]*v[2] + v[3]*v[3];
  float mean, rstd;
  block_ln_stats(s1f, s2f, mean, rstd);
  ushort4 o;
  o.x = f2bf((v[0] - mean) * rstd); o.y = f2bf((v[1] - mean) * rstd);
  o.z = f2bf((v[2] - mean) * rstd); o.w = f2bf((v[3] - mean) * rstd);
  ((ushort4*)(xc + (size_t)t * DD))[tid] = o;
}

// ---- out = layernorm(h + sum_z c2part[z] + c_b2, o_g, o_b) ----
__global__ void k_final(const float* __restrict__ h, const float* __restrict__ c2p,
                        const float* __restrict__ cb2, const float* __restrict__ og,
                        const float* __restrict__ ob, float* __restrict__ out) {
  int t = blockIdx.x, tid = threadIdx.x;
  float4 hv = ((const float4*)(h + (size_t)t * DD))[tid];
  float ax = 0.f, ay = 0.f, az = 0.f, aw = 0.f;
  #pragma unroll
  for (int z = 0; z < KSC2; ++z) {
    float4 u = ((const float4*)(c2p + (size_t)z * TOK * DD + (size_t)t * DD))[tid];
    ax += u.x; ay += u.y; az += u.z; aw += u.w;
  }
  float4 cb = ((const float4*)cb2)[tid];
  float v[4] = {hv.x + ax + cb.x, hv.y + ay + cb.y, hv.z + az + cb.z, hv.w + aw + cb.w};
  float s1 = v[0] + v[1] + v[2] + v[3];
  float s2 = v[0]*v[0] + v[1]*v[1] + v[2]*v[2] + v[3]*v[3];
  float mean, rstd;
  block_ln_stats(s1, s2, mean, rstd);
  float4 gv = ((const float4*)og)[tid];
  float4 bv = ((const float4*)ob)[tid];
  float4 o;
  o.x = (v[0] - mean) * rstd * gv.x + bv.x;
  o.y = (v[1] - mean) * rstd * gv.y + bv.y;
  o.z = (v[2] - mean) * rstd * gv.z + bv.z;
  o.w = (v[3] - mean) * rstd * gv.w + bv.w;
  ((float4*)(out + (size_t)t * DD))[tid] = o;
}

extern "C" void kernel_launch(void* const* d_in, const int* in_sizes, int n_in,
                              void* d_out, int out_size, void* d_ws, size_t ws_size,
                              hipStream_t stream) {
  (void)in_sizes; (void)n_in; (void)out_size; (void)ws_size;
  const float* x      = (const float*)d_in[0];
  const float* r_ln_g = (const float*)d_in[1];
  const float* r_ln_b = (const float*)d_in[2];
  const float* r_w1   = (const float*)d_in[3];
  const float* r_b1   = (const float*)d_in[4];
  const float* r_w2   = (const float*)d_in[5];
  const float* r_b2   = (const float*)d_in[6];
  const float* temp   = (const float*)d_in[7];
  const float* e_ln_g = (const float*)d_in[8];
  const float* e_ln_b = (const float*)d_in[9];
  const float* e_w1   = (const float*)d_in[10];
  const float* e_b1   = (const float*)d_in[11];
  const float* e_w2   = (const float*)d_in[12];
  const float* e_b2   = (const float*)d_in[13];
  const float* c_ln_g = (const float*)d_in[14];
  const float* c_ln_b = (const float*)d_in[15];
  const float* c_w1   = (const float*)d_in[16];
  const float* c_b1   = (const float*)d_in[17];
  const float* c_w2   = (const float*)d_in[18];
  const float* c_b2   = (const float*)d_in[19];
  const float* o_ln_g = (const float*)d_in[20];
  const float* o_ln_b = (const float*)d_in[21];
  float* out = (float*)d_out;

  char* base = (char*)d_ws;
  long long cur = 0;
  auto take = [&](long long sz) { char* r = base + cur; cur += (sz + 255) & ~255LL; return r; };

  float* h      = (float*)take(8388608);            // [2048,1024] fp32
  float* xh32   = (float*)take(8388608);            // xhat fp32
  unsigned short* xhi = (unsigned short*)take(4194304); // xhat bf16 hi
  unsigned short* xlo = (unsigned short*)take(4194304); // xhat bf16 lo
  unsigned short* WrH = (unsigned short*)take(8388608); // router W1^T*g hi
  unsigned short* WrL = (unsigned short*)take(8388608);
  float* Wr32   = (float*)take(16777216);           // router W1^T*g fp32 (triage)
  float* biasr  = (float*)take(16384);
  float* lgp    = (float*)take((long long)(RH/128) * TOK * NE * 4); // 2 MB logit partials
  int*   flag   = (int*)take(8192);
  float* lg32   = (float*)take(65536);              // exact fp32 logits (triage accum)
  int*   sel_i  = (int*)take(16384);                // [TOK][2] expert idx
  float* sel_p  = (float*)take(16384);              // [TOK][2] gate prob
  int*   cnt    = (int*)take(256);
  int*   off    = (int*)take(256);
  int*   fillc  = (int*)take(256);
  int*   tile_e = (int*)take(256);
  int*   tile_r0= (int*)take(256);
  int*   ntiles = (int*)take(256);
  int*   nflag  = (int*)take(256);
  int*   ftok   = (int*)take(TOK * 4);
  int*   slotarr= (int*)take(16384);                // [TOK][2] -> pair slot
  int*   tok_of = (int*)take(MAXROWS * 4);          // pair slot -> token
  unsigned short* We1 = (unsigned short*)take(67108864); // [8][4096,1024]
  float* be1    = (float*)take(131072);
  unsigned short* We2 = (unsigned short*)take(67108864); // [8][1024,4096]
  unsigned short* Wc1 = (unsigned short*)take(4194304);
  float* bc1    = (float*)take(8192);
  unsigned short* Wc2 = (unsigned short*)take(4194304);
  unsigned short* xc  = (unsigned short*)take(4194304);
  unsigned short* c1  = (unsigned short*)take(8388608);
  unsigned short* F1g = (unsigned short*)take((long long)MAXROWS * RH * 2);   // 40 MB
  unsigned short* pairout = (unsigned short*)take((long long)MAXROWS * DD * 2); // 10 MB
  float* c2part = (float*)take((long long)KSC2 * TOK * DD * 4);               // 16.8 MB

  // prep (also zeroes bucketing state) + weight conversion
  k_prep<<<TOK, 256, 0, stream>>>(x, h, xh32, xhi, xlo, cnt, fillc, nflag, tok_of);
  k_tconv_split<<<dim3(RH/32, DD/32, 1), 256, 0, stream>>>(r_w1, r_ln_g, WrH, WrL, Wr32, DD, RH);
  k_tconv<<<dim3(RH/64, DD/64, NE), 256, 0, stream>>>(e_w1, e_ln_g, We1, DD, RH,
      (long long)DD*RH, (long long)DD, (long long)RH*DD);
  k_tconv<<<dim3(DD/64, HE/64, NE), 256, 0, stream>>>(e_w2, nullptr, We2, HE, DD,
      (long long)HE*DD, 0LL, (long long)DD*HE);
  k_tconv<<<dim3(CH/64, DD/64, 1), 256, 0, stream>>>(c_w1, c_ln_g, Wc1, DD, CH, 0LL, 0LL, 0LL);
  k_tconv<<<dim3(DD/64, CH/64, 1), 256, 0, stream>>>(c_w2, nullptr, Wc2, CH, DD, 0LL, 0LL, 0LL);
  k_foldbias<<<dim3(RH/256, 1), 256, 0, stream>>>(r_w1, r_ln_b, r_b1, biasr, DD, RH, 0LL, 0LL, 0LL, 0LL);
  k_foldbias<<<dim3(RH/256, NE), 256, 0, stream>>>(e_w1, e_ln_b, e_b1, be1, DD, RH,
      (long long)DD*RH, (long long)DD, (long long)RH, (long long)RH);
  k_foldbias<<<dim3(CH/256, 1), 256, 0, stream>>>(c_w1, c_ln_b, c_b1, bc1, DD, CH, 0LL, 0LL, 0LL, 0LL);

  // router (split precision, fused GEMM2 partials) + top2 + near-tie triage
  k_gemm_split<<<dim3(RH/128, TOK/128, 1), 256, 0, stream>>>(xhi, xlo, WrH, WrL, biasr,
      r_w2, lgp, DD);
  k_gate1<<<TOK/256, 256, 0, stream>>>(lgp, r_b2, temp, sel_i, sel_p, flag, lg32, nflag, ftok);
  k_triage2<<<dim3(RH/64, 32), 256, 0, stream>>>(nflag, ftok, xh32, Wr32, biasr, r_w2, lg32);
  k_gate2<<<TOK/256, 256, 0, stream>>>(flag, lg32, r_b2, temp, sel_i, sel_p, cnt);

  // bucket (token,expert) pairs by expert
  k_offsets<<<1, 64, 0, stream>>>(cnt, off, tile_e, tile_r0, ntiles);
  k_fill<<<TOK/256, 256, 0, stream>>>(sel_i, off, fillc, slotarr, tok_of);

  // sparse grouped expert FFN (only selected pairs); g2 = 64-col tiles, direct bf16 out
  k_gemm_g1<<<dim3(RH/128, MAXTILE), 256, 0, stream>>>(xhi, We1, be1, F1g,
      tok_of, tile_e, tile_r0, ntiles);
  k_gemm_g2n<<<dim3(DD/64, MAXTILE), 256, 0, stream>>>(F1g, We2, pairout,
      tile_e, tile_r0, ntiles);

  // combine + combiner MLP (64-col tiles; c2 split-K=2) + residual/output LN
  k_combine2<<<TOK, 256, 0, stream>>>(slotarr, sel_i, sel_p, pairout, e_b2, xc);
  k_gemm_n64<1,1><<<dim3(CH/64, TOK/128, 1), 256, 0, stream>>>(xc, Wc1, bc1, (void*)c1,
      CH, DD, DD, 0LL);
  k_gemm_n64<0,0><<<dim3(DD/64, TOK/128, KSC2), 256, 0, stream>>>(c1, Wc2, nullptr,
      (void*)c2part, DD, CH, CH/KSC2, (long long)TOK * DD);
  k_final<<<TOK, 256, 0, stream>>>(h, c2part, c_b2, o_ln_g, o_ln_b, out);
}